// Round 3
// baseline (1219.214 us; speedup 1.0000x reference)
//
#include <hip/hip_runtime.h>
#include <math.h>

#define N_NODES 10000
#define DIN 128
#define HID 32
#define EMB 16

#define TBS 256                         // threads per block (softmax kernel)
#define RB 4                            // rows per block (10000 % 4 == 0)
#define NF4 2500                        // N_NODES / 4
#define NIT ((NF4 + TBS - 1) / TBS)     // 10 chunk iterations
#define NB (N_NODES / RB)               // 2500 blocks

typedef float fx4 __attribute__((ext_vector_type(4)));

// hardware transcendentals: v_exp_f32 = 2^x, v_log_f32 = log2(x)
#define EXP2F(x) __builtin_amdgcn_exp2f(x)
#define LOG2F(x) __builtin_amdgcn_logf(x)

// ---------------- encoder: H = relu(X@W1+b1)@W2+b2 ; Hn = H/||H|| -----------
__global__ __launch_bounds__(256) void encoder_kernel(
    const float* __restrict__ X, const float* __restrict__ W1,
    const float* __restrict__ b1, const float* __restrict__ W2,
    const float* __restrict__ b2, float* __restrict__ Hout,
    float* __restrict__ Hn)
{
    __shared__ float sW1[DIN * HID];
    __shared__ float sW2[HID * EMB];
    __shared__ float sb1[HID];
    __shared__ float sb2[EMB];
    const int t = threadIdx.x;
    for (int k = t; k < DIN * HID; k += 256) sW1[k] = W1[k];
    for (int k = t; k < HID * EMB; k += 256) sW2[k] = W2[k];
    if (t < HID) sb1[t] = b1[t];
    if (t < EMB) sb2[t] = b2[t];
    __syncthreads();

    const int row = blockIdx.x * 256 + t;
    if (row >= N_NODES) return;

    float h1[HID];
#pragma unroll
    for (int h = 0; h < HID; ++h) h1[h] = sb1[h];

    const float4* xr = (const float4*)(X + (size_t)row * DIN);
#pragma unroll
    for (int k4 = 0; k4 < DIN / 4; ++k4) {
        float4 xv = xr[k4];
        const float* w = &sW1[(k4 * 4) * HID];
#pragma unroll
        for (int h = 0; h < HID; ++h) h1[h] = fmaf(xv.x, w[h], h1[h]);
#pragma unroll
        for (int h = 0; h < HID; ++h) h1[h] = fmaf(xv.y, w[HID + h], h1[h]);
#pragma unroll
        for (int h = 0; h < HID; ++h) h1[h] = fmaf(xv.z, w[2 * HID + h], h1[h]);
#pragma unroll
        for (int h = 0; h < HID; ++h) h1[h] = fmaf(xv.w, w[3 * HID + h], h1[h]);
    }

    float e[EMB];
#pragma unroll
    for (int j = 0; j < EMB; ++j) e[j] = sb2[j];
#pragma unroll
    for (int h = 0; h < HID; ++h) {
        float v = fmaxf(h1[h], 0.0f);
#pragma unroll
        for (int j = 0; j < EMB; ++j) e[j] = fmaf(v, sW2[h * EMB + j], e[j]);
    }

    float s = 0.0f;
#pragma unroll
    for (int j = 0; j < EMB; ++j) s = fmaf(e[j], e[j], s);
    float nrm = sqrtf(s);
    float inv = 1.0f / fmaxf(nrm, 1e-12f);

    float* ho = Hout + (size_t)row * EMB;
    float* hn = Hn + (size_t)row * EMB;
#pragma unroll
    for (int j = 0; j < EMB; ++j) ho[j] = e[j];
#pragma unroll
    for (int j = 0; j < EMB; ++j) hn[j] = e[j] * inv;
}

// ---------------- fused logits + row softmax over N×N --------------------
// x = alpha*log(a+1e-12) + cl*dot, a<=1, dot<=1  =>  x <= cl (constant).
// Softmax shift-invariance with constant shift cl:
//   e = exp(x - cl) = exp2( alpha*log2(a+1e-12) + cl2*dot - cl2 ),
//   cl2 = cl*log2(e).  e in (0,1]; diagonal keeps row sums well above 0.
// => no max pass, no per-element state; streaming recompute in 2 passes.

__device__ __forceinline__ float dot16u(const float* h, const fx4& b0,
                                        const fx4& b1, const fx4& b2,
                                        const fx4& b3)
{
    float s = h[0] * b0.x;
    s = fmaf(h[1],  b0.y, s);
    s = fmaf(h[2],  b0.z, s);
    s = fmaf(h[3],  b0.w, s);
    s = fmaf(h[4],  b1.x, s);
    s = fmaf(h[5],  b1.y, s);
    s = fmaf(h[6],  b1.z, s);
    s = fmaf(h[7],  b1.w, s);
    s = fmaf(h[8],  b2.x, s);
    s = fmaf(h[9],  b2.y, s);
    s = fmaf(h[10], b2.z, s);
    s = fmaf(h[11], b2.w, s);
    s = fmaf(h[12], b3.x, s);
    s = fmaf(h[13], b3.y, s);
    s = fmaf(h[14], b3.z, s);
    s = fmaf(h[15], b3.w, s);
    return s;
}

__global__ __launch_bounds__(TBS, 8) void softmax_kernel(
    const float* __restrict__ A, const float* __restrict__ Hn,
    const float* __restrict__ p_log_tau, const float* __restrict__ p_raw_alpha,
    float* __restrict__ Wout)
{
    const int t = threadIdx.x;
    const int row0 = blockIdx.x * RB;

    const float tau = fminf(fmaxf(__expf(p_log_tau[0]), 0.1f), 10.0f);
    const float alpha = 1.0f / (1.0f + __expf(-p_raw_alpha[0]));
    const float cl  = (1.0f - alpha) / tau;
    const float cl2 = cl * 1.4426950408889634f;   // cl * log2(e)

    // Block-uniform query rows -> force into SGPRs (keeps VGPR count low).
    float shi[RB][EMB];
#pragma unroll
    for (int r = 0; r < RB; ++r) {
        const fx4* hp = (const fx4*)(Hn + (size_t)(row0 + r) * EMB);
#pragma unroll
        for (int p = 0; p < 4; ++p) {
            fx4 v = hp[p];
            shi[r][4 * p + 0] = __int_as_float(__builtin_amdgcn_readfirstlane(__float_as_int(v.x)));
            shi[r][4 * p + 1] = __int_as_float(__builtin_amdgcn_readfirstlane(__float_as_int(v.y)));
            shi[r][4 * p + 2] = __int_as_float(__builtin_amdgcn_readfirstlane(__float_as_int(v.z)));
            shi[r][4 * p + 3] = __int_as_float(__builtin_amdgcn_readfirstlane(__float_as_int(v.w)));
        }
    }

    const fx4* Hn4 = (const fx4*)Hn;

    // ---- pass 1: row sums of e (A read stays cached for pass 2) ----
    float sloc[RB];
#pragma unroll
    for (int r = 0; r < RB; ++r) sloc[r] = 0.0f;

#pragma unroll 2
    for (int it = 0; it < NIT; ++it) {
        const int f4 = it * TBS + t;
        if (f4 < NF4) {
            fx4 av[RB];
#pragma unroll
            for (int r = 0; r < RB; ++r)
                av[r] = *((const fx4*)(A + (size_t)(row0 + r) * N_NODES) + f4);
#pragma unroll
            for (int d = 0; d < 4; ++d) {
                const int j = f4 * 4 + d;
                const fx4 b0 = Hn4[j * 4 + 0];
                const fx4 b1 = Hn4[j * 4 + 1];
                const fx4 b2 = Hn4[j * 4 + 2];
                const fx4 b3 = Hn4[j * 4 + 3];
#pragma unroll
                for (int r = 0; r < RB; ++r) {
                    float a = (d == 0) ? av[r].x
                            : (d == 1) ? av[r].y
                            : (d == 2) ? av[r].z
                                       : av[r].w;
                    float lgm = fmaf(alpha, LOG2F(a + 1e-12f), -cl2);
                    float dv = dot16u(shi[r], b0, b1, b2, b3);
                    sloc[r] += EXP2F(fmaf(cl2, dv, lgm));
                }
            }
        }
    }

    // ---- block reduction: sum per row ----
    __shared__ float red[RB][TBS / 64];
    __shared__ float rbc[RB];
    const int lane = t & 63;
    const int wave = t >> 6;
#pragma unroll
    for (int r = 0; r < RB; ++r) {
        float v = sloc[r];
#pragma unroll
        for (int off = 32; off >= 1; off >>= 1) v += __shfl_down(v, off, 64);
        if (lane == 0) red[r][wave] = v;
    }
    __syncthreads();
    if (t < RB) {
        float v = red[t][0];
#pragma unroll
        for (int w = 1; w < TBS / 64; ++w) v += red[t][w];
        rbc[t] = 1.0f / v;
    }
    __syncthreads();
    float invl[RB];
#pragma unroll
    for (int r = 0; r < RB; ++r) invl[r] = rbc[r];

    // ---- pass 2: recompute e, write normalized (reverse order: tail of A
    //      is still L2/L3-hot from pass 1) ----
#pragma unroll 2
    for (int it = NIT - 1; it >= 0; --it) {
        const int f4 = it * TBS + t;
        if (f4 < NF4) {
            fx4 av[RB];
#pragma unroll
            for (int r = 0; r < RB; ++r)
                av[r] = __builtin_nontemporal_load(
                    (const fx4*)(A + (size_t)(row0 + r) * N_NODES) + f4);
            fx4 o[RB];
#pragma unroll
            for (int d = 0; d < 4; ++d) {
                const int j = f4 * 4 + d;
                const fx4 b0 = Hn4[j * 4 + 0];
                const fx4 b1 = Hn4[j * 4 + 1];
                const fx4 b2 = Hn4[j * 4 + 2];
                const fx4 b3 = Hn4[j * 4 + 3];
#pragma unroll
                for (int r = 0; r < RB; ++r) {
                    float a = (d == 0) ? av[r].x
                            : (d == 1) ? av[r].y
                            : (d == 2) ? av[r].z
                                       : av[r].w;
                    float lgm = fmaf(alpha, LOG2F(a + 1e-12f), -cl2);
                    float dv = dot16u(shi[r], b0, b1, b2, b3);
                    float e = EXP2F(fmaf(cl2, dv, lgm)) * invl[r];
                    if (d == 0)      o[r].x = e;
                    else if (d == 1) o[r].y = e;
                    else if (d == 2) o[r].z = e;
                    else             o[r].w = e;
                }
            }
#pragma unroll
            for (int r = 0; r < RB; ++r)
                __builtin_nontemporal_store(
                    o[r], (fx4*)(Wout + (size_t)(row0 + r) * N_NODES) + f4);
        }
    }
}

extern "C" void kernel_launch(void* const* d_in, const int* in_sizes, int n_in,
                              void* d_out, int out_size, void* d_ws, size_t ws_size,
                              hipStream_t stream) {
    const float* X        = (const float*)d_in[0];
    const float* A        = (const float*)d_in[1];
    const float* W1       = (const float*)d_in[2];
    const float* b1       = (const float*)d_in[3];
    const float* W2       = (const float*)d_in[4];
    const float* b2       = (const float*)d_in[5];
    const float* log_tau  = (const float*)d_in[6];
    const float* raw_alpha= (const float*)d_in[7];

    float* Wout = (float*)d_out;
    float* Hout = (float*)d_out + (size_t)N_NODES * N_NODES;
    float* Hn   = (float*)d_ws;   // 10000*16 floats = 640 KB scratch

    encoder_kernel<<<(N_NODES + 255) / 256, 256, 0, stream>>>(X, W1, b1, W2, b2, Hout, Hn);

    softmax_kernel<<<NB, TBS, 0, stream>>>(A, Hn, log_tau, raw_alpha, Wout);
}

// Round 4
// 1102.310 us; speedup vs baseline: 1.1061x; 1.1061x over previous
//
#include <hip/hip_runtime.h>
#include <math.h>

#define N_NODES 10000
#define DIN 128
#define HID 32
#define EMB 16

// ---- softmax decomposition ----
#define RBLK 256                        // threads per block = output rows per block
#define G    50                         // column groups
#define JG   200                        // columns per group  (G*JG = N_NODES)
#define JT   20                         // columns per LDS tile (JG % JT == 0)
#define NTILE (JG / JT)                 // 10 tiles per group
#define LSTR 24                         // LDS row stride in floats (JT + 4 pad, 96 B: 16B-aligned)
#define NRB  ((N_NODES + RBLK - 1) / RBLK)   // 40 row-blocks (last has 16 valid rows)

typedef float fx4 __attribute__((ext_vector_type(4)));

// hardware transcendentals: v_exp_f32 = 2^x, v_log_f32 = log2(x)
#define EXP2F(x) __builtin_amdgcn_exp2f(x)
#define LOG2F(x) __builtin_amdgcn_logf(x)

// ---------------- encoder: H = relu(X@W1+b1)@W2+b2 ; Hn = H/||H|| -----------
__global__ __launch_bounds__(256) void encoder_kernel(
    const float* __restrict__ X, const float* __restrict__ W1,
    const float* __restrict__ b1, const float* __restrict__ W2,
    const float* __restrict__ b2, float* __restrict__ Hout,
    float* __restrict__ Hn)
{
    __shared__ float sW1[DIN * HID];
    __shared__ float sW2[HID * EMB];
    __shared__ float sb1[HID];
    __shared__ float sb2[EMB];
    const int t = threadIdx.x;
    for (int k = t; k < DIN * HID; k += 256) sW1[k] = W1[k];
    for (int k = t; k < HID * EMB; k += 256) sW2[k] = W2[k];
    if (t < HID) sb1[t] = b1[t];
    if (t < EMB) sb2[t] = b2[t];
    __syncthreads();

    const int row = blockIdx.x * 256 + t;
    if (row >= N_NODES) return;

    float h1[HID];
#pragma unroll
    for (int h = 0; h < HID; ++h) h1[h] = sb1[h];

    const float4* xr = (const float4*)(X + (size_t)row * DIN);
#pragma unroll
    for (int k4 = 0; k4 < DIN / 4; ++k4) {
        float4 xv = xr[k4];
        const float* w = &sW1[(k4 * 4) * HID];
#pragma unroll
        for (int h = 0; h < HID; ++h) h1[h] = fmaf(xv.x, w[h], h1[h]);
#pragma unroll
        for (int h = 0; h < HID; ++h) h1[h] = fmaf(xv.y, w[HID + h], h1[h]);
#pragma unroll
        for (int h = 0; h < HID; ++h) h1[h] = fmaf(xv.z, w[2 * HID + h], h1[h]);
#pragma unroll
        for (int h = 0; h < HID; ++h) h1[h] = fmaf(xv.w, w[3 * HID + h], h1[h]);
    }

    float e[EMB];
#pragma unroll
    for (int j = 0; j < EMB; ++j) e[j] = sb2[j];
#pragma unroll
    for (int h = 0; h < HID; ++h) {
        float v = fmaxf(h1[h], 0.0f);
#pragma unroll
        for (int j = 0; j < EMB; ++j) e[j] = fmaf(v, sW2[h * EMB + j], e[j]);
    }

    float s = 0.0f;
#pragma unroll
    for (int j = 0; j < EMB; ++j) s = fmaf(e[j], e[j], s);
    float nrm = sqrtf(s);
    float inv = 1.0f / fmaxf(nrm, 1e-12f);

    float* ho = Hout + (size_t)row * EMB;
    float* hn = Hn + (size_t)row * EMB;
#pragma unroll
    for (int j = 0; j < EMB; ++j) ho[j] = e[j];
#pragma unroll
    for (int j = 0; j < EMB; ++j) hn[j] = e[j] * inv;
}

// ---------------- fused logits + row softmax over N×N --------------------
// x = alpha*log(a+1e-12) + cl*dot, a<=1, dot<=1  =>  x <= cl (constant).
// e = exp2(alpha*log2(a+1e-12) + cl2*dot - cl2), cl2 = cl*log2(e); e in (0,1].
// Layout: each LANE owns one output row; the wave marches columns together
// => Hn[j] is wave-uniform (scalar/broadcast load, 1 line/wave), row sums are
// per-lane scalars. A/W stay coalesced via an LDS transpose tile.

__device__ __forceinline__ float dot16f(const float4& ha, const float4& hb,
                                        const float4& hc, const float4& hd,
                                        const float4& b0, const float4& b1,
                                        const float4& b2, const float4& b3)
{
    float s = ha.x * b0.x;
    s = fmaf(ha.y, b0.y, s);
    s = fmaf(ha.z, b0.z, s);
    s = fmaf(ha.w, b0.w, s);
    s = fmaf(hb.x, b1.x, s);
    s = fmaf(hb.y, b1.y, s);
    s = fmaf(hb.z, b1.z, s);
    s = fmaf(hb.w, b1.w, s);
    s = fmaf(hc.x, b2.x, s);
    s = fmaf(hc.y, b2.y, s);
    s = fmaf(hc.z, b2.z, s);
    s = fmaf(hc.w, b2.w, s);
    s = fmaf(hd.x, b3.x, s);
    s = fmaf(hd.y, b3.y, s);
    s = fmaf(hd.z, b3.z, s);
    s = fmaf(hd.w, b3.w, s);
    return s;
}

// ---- kernel 1: per-(group,row) partial sums of e ----
__global__ __launch_bounds__(RBLK, 6) void partial_kernel(
    const float* __restrict__ A, const float* __restrict__ Hn,
    const float* __restrict__ p_log_tau, const float* __restrict__ p_raw_alpha,
    float* __restrict__ partial)
{
    __shared__ float lds[RBLK * LSTR];          // 24576 B
    const int t = threadIdx.x;
    const int row0 = blockIdx.x * RBLK;
    const int g = blockIdx.y;
    const int j0 = g * JG;

    const float tau = fminf(fmaxf(__expf(p_log_tau[0]), 0.1f), 10.0f);
    const float alpha = 1.0f / (1.0f + __expf(-p_raw_alpha[0]));
    const float cl2 = ((1.0f - alpha) / tau) * 1.4426950408889634f;

    // this lane's query row (clamped for the 16-row tail block)
    const int rowc = min(row0 + t, N_NODES - 1);
    const float4* hp = (const float4*)(Hn + (size_t)rowc * EMB);
    const float4 ha = hp[0], hb = hp[1], hc = hp[2], hd = hp[3];

    float sloc = 0.0f;

    for (int tile = 0; tile < NTILE; ++tile) {
        const int jt0 = j0 + tile * JT;
        __syncthreads();                        // protect prev tile's reads
        // stage: 256 rows x 20 cols, 5 float4 per thread, coalesced global reads
#pragma unroll
        for (int k = 0; k < 5; ++k) {
            const int f = k * RBLK + t;         // 0..1279
            const int r = f / 5, q = f % 5;
            const int grow = row0 + r;
            if (grow < N_NODES) {
                float4 v = *(const float4*)(A + (size_t)grow * N_NODES + jt0 + q * 4);
                *(float4*)&lds[r * LSTR + q * 4] = v;
            }
        }
        __syncthreads();
        // compute 20 columns; lane reads its own LDS row (b128, ~4-way)
#pragma unroll
        for (int jq = 0; jq < 5; ++jq) {
            const float4 av = *(const float4*)&lds[t * LSTR + jq * 4];
#pragma unroll
            for (int d = 0; d < 4; ++d) {
                const int j = jt0 + jq * 4 + d;                 // wave-uniform
                const float4* bp = (const float4*)(Hn + (size_t)j * EMB);
                const float4 b0 = bp[0], b1 = bp[1], b2 = bp[2], b3 = bp[3];
                const float a = (d == 0) ? av.x : (d == 1) ? av.y
                              : (d == 2) ? av.z : av.w;
                const float lgm = fmaf(alpha, LOG2F(a + 1e-12f), -cl2);
                const float dv = dot16f(ha, hb, hc, hd, b0, b1, b2, b3);
                sloc += EXP2F(fmaf(cl2, dv, lgm));
            }
        }
    }

    const int row = row0 + t;
    if (row < N_NODES)
        partial[(size_t)g * N_NODES + row] = sloc;              // coalesced
}

// ---- kernel 2: reduce partials, recompute e, write normalized W ----
__global__ __launch_bounds__(RBLK, 6) void norm_kernel(
    const float* __restrict__ A, const float* __restrict__ Hn,
    const float* __restrict__ p_log_tau, const float* __restrict__ p_raw_alpha,
    const float* __restrict__ partial, float* __restrict__ Wout)
{
    __shared__ float lds[RBLK * LSTR];
    const int t = threadIdx.x;
    const int row0 = blockIdx.x * RBLK;
    const int g = blockIdx.y;
    const int j0 = g * JG;

    const float tau = fminf(fmaxf(__expf(p_log_tau[0]), 0.1f), 10.0f);
    const float alpha = 1.0f / (1.0f + __expf(-p_raw_alpha[0]));
    const float cl2 = ((1.0f - alpha) / tau) * 1.4426950408889634f;

    const int rowc = min(row0 + t, N_NODES - 1);
    const float4* hp = (const float4*)(Hn + (size_t)rowc * EMB);
    const float4 ha = hp[0], hb = hp[1], hc = hp[2], hd = hp[3];

    // total row sum across groups (coalesced per g2; clamped index for tail)
    float tot = 0.0f;
#pragma unroll 5
    for (int g2 = 0; g2 < G; ++g2)
        tot += partial[(size_t)g2 * N_NODES + rowc];
    const float invl = 1.0f / tot;

    for (int tile = 0; tile < NTILE; ++tile) {
        const int jt0 = j0 + tile * JT;
        __syncthreads();
#pragma unroll
        for (int k = 0; k < 5; ++k) {
            const int f = k * RBLK + t;
            const int r = f / 5, q = f % 5;
            const int grow = row0 + r;
            if (grow < N_NODES) {
                float4 v = *(const float4*)(A + (size_t)grow * N_NODES + jt0 + q * 4);
                *(float4*)&lds[r * LSTR + q * 4] = v;
            }
        }
        __syncthreads();
#pragma unroll
        for (int jq = 0; jq < 5; ++jq) {
            const float4 av = *(const float4*)&lds[t * LSTR + jq * 4];
            float4 ev;
#pragma unroll
            for (int d = 0; d < 4; ++d) {
                const int j = jt0 + jq * 4 + d;
                const float4* bp = (const float4*)(Hn + (size_t)j * EMB);
                const float4 b0 = bp[0], b1 = bp[1], b2 = bp[2], b3 = bp[3];
                const float a = (d == 0) ? av.x : (d == 1) ? av.y
                              : (d == 2) ? av.z : av.w;
                const float lgm = fmaf(alpha, LOG2F(a + 1e-12f), -cl2);
                const float dv = dot16f(ha, hb, hc, hd, b0, b1, b2, b3);
                const float e = EXP2F(fmaf(cl2, dv, lgm)) * invl;
                if (d == 0)      ev.x = e;
                else if (d == 1) ev.y = e;
                else if (d == 2) ev.z = e;
                else             ev.w = e;
            }
            *(float4*)&lds[t * LSTR + jq * 4] = ev;   // in-place, own slot
        }
        __syncthreads();
        // writeback: coalesced global float4 stores (L2 combines partial lines)
#pragma unroll
        for (int k = 0; k < 5; ++k) {
            const int f = k * RBLK + t;
            const int r = f / 5, q = f % 5;
            const int grow = row0 + r;
            if (grow < N_NODES) {
                float4 v = *(const float4*)&lds[r * LSTR + q * 4];
                *(float4*)(Wout + (size_t)grow * N_NODES + jt0 + q * 4) = v;
            }
        }
    }
}

extern "C" void kernel_launch(void* const* d_in, const int* in_sizes, int n_in,
                              void* d_out, int out_size, void* d_ws, size_t ws_size,
                              hipStream_t stream) {
    const float* X        = (const float*)d_in[0];
    const float* A        = (const float*)d_in[1];
    const float* W1       = (const float*)d_in[2];
    const float* b1       = (const float*)d_in[3];
    const float* W2       = (const float*)d_in[4];
    const float* b2       = (const float*)d_in[5];
    const float* log_tau  = (const float*)d_in[6];
    const float* raw_alpha= (const float*)d_in[7];

    float* Wout = (float*)d_out;
    float* Hout = (float*)d_out + (size_t)N_NODES * N_NODES;
    float* Hn   = (float*)d_ws;                              // 160000 floats
    float* partial = (float*)d_ws + (size_t)N_NODES * EMB;   // G*N = 500000 floats (2 MB)

    encoder_kernel<<<(N_NODES + 255) / 256, 256, 0, stream>>>(X, W1, b1, W2, b2, Hout, Hn);

    dim3 grid(NRB, G);
    partial_kernel<<<grid, RBLK, 0, stream>>>(A, Hn, log_tau, raw_alpha, partial);
    norm_kernel<<<grid, RBLK, 0, stream>>>(A, Hn, log_tau, raw_alpha, partial, Wout);
}